// Round 4
// baseline (775.450 us; speedup 1.0000x reference)
//
#include <hip/hip_runtime.h>
#include <hip/hip_bf16.h>
#include <math.h>
#include <cstdint>

#define KDIM 4096   // IN_FEATURES
#define ODIM 4096   // OUT_FEATURES
#define MDIM 8192   // N_ROWS
#define EPSF 1e-6f
#define TM05 2047.5f   // threshold(=2048) - 0.5

typedef __bf16 bf16x8 __attribute__((ext_vector_type(8)));
typedef float f32x4 __attribute__((ext_vector_type(4)));
typedef unsigned short u16;

#define XY_DELTA (MDIM * KDIM)   // Xb -> Yb   (in u16 elements)
#define CD_DELTA (ODIM * KDIM)   // Cb -> C2b  (in u16 elements)

// ---- m201-template GEMM geometry ----
// 256x256 block tile, BK=64, 512 threads = 8 waves (2 M-halves x 4 N-quarters),
// per-wave output 128x64 (acc[8][4]). LDS: 2 buffers x (A 32KB + B 32KB) = 128KB.
// 8 phases per iteration (2 K-tiles of 64); 16 MFMA per phase.
// Phases decomposed by (m-half, k-step): reads per phase = 8,8,4,4 (even-ish).
// ONE barrier per phase (trailing, inline-asm so no compiler-inserted vmcnt
// drain can attach); counted vmcnt(4) fused into the barrier twice per
// iteration, drain-to-0 only in the last iteration.
#define NITER (KDIM / 128)   // 32 iterations x 2 K-tiles of 64

__device__ __forceinline__ u16 f2bf(float f) {
  __hip_bfloat16 h = __float2bfloat16(f);
  return __builtin_bit_cast(u16, h);
}
__device__ __forceinline__ float bf2f(u16 b) {
  unsigned int u = ((unsigned int)b) << 16;
  return __builtin_bit_cast(float, u);
}

// async global->LDS direct copy, 16 B per lane (dst must be lane-linear).
__device__ __forceinline__ void async_cp16(void* lds, const void* g) {
  __builtin_amdgcn_global_load_lds(
      (__attribute__((address_space(1))) void*)(uintptr_t)g,
      (__attribute__((address_space(3))) void*)lds, 16, 0, 0);
}

// ---------------- prep: X -> bf16 X, bf16 Y = x*(1-x) ----------------
__global__ void prep_x_kernel(const float4* __restrict__ x4,
                              ushort4* __restrict__ Xb,
                              ushort4* __restrict__ Yb) {
  int i = blockIdx.x * blockDim.x + threadIdx.x;
  float4 v = x4[i];
  ushort4 xo, yo;
  xo.x = f2bf(v.x); xo.y = f2bf(v.y); xo.z = f2bf(v.z); xo.w = f2bf(v.w);
  yo.x = f2bf(v.x * (1.0f - v.x));
  yo.y = f2bf(v.y * (1.0f - v.y));
  yo.z = f2bf(v.z * (1.0f - v.z));
  yo.w = f2bf(v.w * (1.0f - v.w));
  Xb[i] = xo;
  Yb[i] = yo;
}

// ---------------- prep: W -> bf16 C=2*sig(w)-1, bf16 C2=C*C, sums ----------------
__device__ __forceinline__ void wcomp(float w, u16& cb, u16& c2b, float& sd, float& sde) {
  float pw = 1.0f / (1.0f + __expf(-w));
  float c  = 2.0f * pw - 1.0f;
  float d  = 1.0f - pw;
  cb  = f2bf(c);
  c2b = f2bf(c * c);
  sd  += d;
  sde += d * pw;   // d*(1-d)
}

__global__ void prep_w_kernel(const float4* __restrict__ w4,
                              ushort4* __restrict__ Cb,
                              ushort4* __restrict__ C2b,
                              float* __restrict__ sumd,
                              float* __restrict__ sumde) {
  const int o = blockIdx.x;
  const int t = threadIdx.x;
  const float4* wr = w4 + (size_t)o * (KDIM / 4);
  ushort4* cr  = Cb  + (size_t)o * (KDIM / 4);
  ushort4* c2r = C2b + (size_t)o * (KDIM / 4);
  float sd = 0.f, sde = 0.f;
#pragma unroll
  for (int it = 0; it < KDIM / 4 / 256; ++it) {
    int k4 = t + it * 256;
    float4 w = wr[k4];
    ushort4 co, c2o;
    wcomp(w.x, co.x, c2o.x, sd, sde);
    wcomp(w.y, co.y, c2o.y, sd, sde);
    wcomp(w.z, co.z, c2o.z, sd, sde);
    wcomp(w.w, co.w, c2o.w, sd, sde);
    cr[k4]  = co;
    c2r[k4] = c2o;
  }
#pragma unroll
  for (int off = 32; off > 0; off >>= 1) {
    sd  += __shfl_down(sd, off);
    sde += __shfl_down(sde, off);
  }
  __shared__ float red[8];
  if ((t & 63) == 0) { red[t >> 6] = sd; red[4 + (t >> 6)] = sde; }
  __syncthreads();
  if (t == 0) {
    sumd[o]  = red[0] + red[1] + red[2] + red[3];
    sumde[o] = red[4] + red[5] + red[6] + red[7];
  }
}

// ---------------- 256^2 8-phase GEMM ----------------
// LDS swizzle: row of 64 bf16 = 8 granules of 16B; stored granule = g ^ (row&7);
// staging pre-swizzles the GLOBAL source granule (global_load_lds dst is linear).
//
// Dead-region staging map per iteration s (buf0 = tile 2s, buf1 = tile 2s+1):
//   gp0: buf1.A0 <- t1   gp1: buf1.A1 <- t1
//   gp2: buf0.B0 <- t2   gp3: buf0.B1 <- t2  + vmcnt(4) (retires prev gp6/7 + gp0/1)
//   gp4: buf0.A0 <- t2   gp5: buf0.A1 <- t2
//   gp6: buf1.B0 <- t3   gp7: buf1.B1 <- t3  + vmcnt(4) (retires gp2..gp5)
// Safety of single trailing barrier: any staged region's last readers drained
// at their own lgkmcnt(0) BEFORE the prior phase's barrier; staged data is
// retired by a fused vmcnt before the barrier that precedes its first read.

#define STG2(bb, isB, half, src, koff) do {                                    \
    char* _d = smem + (bb) * 65536 + (isB) * 32768 + (half) * 16384 + tid * 16;\
    const u16* _s = (src) + (size_t)((half) * 128) * KDIM + (koff);            \
    async_cp16(_d, _s);                                                        \
    async_cp16(_d + 8192, _s + (size_t)64 * KDIM);                             \
  } while (0)

#define BAR   asm volatile("s_barrier" ::: "memory")
#define BARV4 asm volatile("s_waitcnt vmcnt(4)\n\ts_barrier" ::: "memory")
#define BARV0 asm volatile("s_waitcnt vmcnt(0)\n\ts_barrier" ::: "memory")

// One phase: 4 A-frag reads (+4 B-frag reads if DOB), stage, drain LDS reads,
// 16 MFMA (m-frags AI..AI+3 x BARR[0..3]), trailing barrier (ENDBAR).
#define PH(bb, AI, MO, GK, BARR, DOB, STG, ENDBAR) {                           \
    const char* Ab = smem + (bb) * 65536;                                      \
    const char* Bb = Ab + 32768;                                               \
    bf16x8 x0 = *(const bf16x8*)(Ab + arow + (MO) + 0 * 2048 + (GK));          \
    bf16x8 x1 = *(const bf16x8*)(Ab + arow + (MO) + 1 * 2048 + (GK));          \
    bf16x8 x2 = *(const bf16x8*)(Ab + arow + (MO) + 2 * 2048 + (GK));          \
    bf16x8 x3 = *(const bf16x8*)(Ab + arow + (MO) + 3 * 2048 + (GK));          \
    if (DOB) {                                                                 \
      _Pragma("unroll") for (int j = 0; j < 4; ++j)                            \
        BARR[j] = *(const bf16x8*)(Bb + brow + j * 2048 + (GK));               \
    }                                                                          \
    STG;                                                                       \
    asm volatile("s_waitcnt lgkmcnt(0)" ::: "memory");                         \
    __builtin_amdgcn_sched_barrier(0);                                         \
    __builtin_amdgcn_s_setprio(1);                                             \
    _Pragma("unroll") for (int j = 0; j < 4; ++j)                              \
      acc[(AI) + 0][j] = __builtin_amdgcn_mfma_f32_16x16x32_bf16(x0, BARR[j], acc[(AI) + 0][j], 0, 0, 0); \
    _Pragma("unroll") for (int j = 0; j < 4; ++j)                              \
      acc[(AI) + 1][j] = __builtin_amdgcn_mfma_f32_16x16x32_bf16(x1, BARR[j], acc[(AI) + 1][j], 0, 0, 0); \
    _Pragma("unroll") for (int j = 0; j < 4; ++j)                              \
      acc[(AI) + 2][j] = __builtin_amdgcn_mfma_f32_16x16x32_bf16(x2, BARR[j], acc[(AI) + 2][j], 0, 0, 0); \
    _Pragma("unroll") for (int j = 0; j < 4; ++j)                              \
      acc[(AI) + 3][j] = __builtin_amdgcn_mfma_f32_16x16x32_bf16(x3, BARR[j], acc[(AI) + 3][j], 0, 0, 0); \
    __builtin_amdgcn_s_setprio(0);                                             \
    ENDBAR;                                                                    \
  }

// PASS 0: var GEMM (Y @ C2^T), writes raw f32 var into out.
// PASS 1: mu GEMM (X @ C^T), reads var from out, applies erfc epilogue in place.
template <int PASS>
__global__ __launch_bounds__(512, 2) void gemm_pass_kernel(
    const u16* __restrict__ Ag, const u16* __restrict__ Bg,
    const float* __restrict__ sumd, const float* __restrict__ sumde,
    float* __restrict__ out) {
  __shared__ __attribute__((aligned(128))) char smem[2 * 65536];

  const int tid  = threadIdx.x;
  const int lane = tid & 63;
  const int wave = tid >> 6;       // 0..7
  const int wr   = wave >> 2;      // M half (128 rows)
  const int wc   = wave & 3;       // N quarter (64 cols)
  const int quad = lane >> 4;
  const int r16  = lane & 15;

  // bijective XCD chunking: 512 wgs = 8 XCDs x 64; each XCD streams 2 N-panels
  const int raw = blockIdx.x;
  const int wg  = (raw & 7) * 64 + (raw >> 3);
  const int n0  = (wg >> 5) * 256;   // 16 N-panels
  const int m0  = (wg & 31) * 256;   // 32 M-panels

  // staging source map (8KB round = 64 rows x 128B): thread t -> row t>>3,
  // dst granule t&7, global granule (t&7)^(row&7)
  const int srow = tid >> 3;
  const int scol = ((tid & 7) ^ (srow & 7)) * 8;
  const u16* gA = Ag + (size_t)(m0 + srow) * KDIM + scol;
  const u16* gB = Bg + (size_t)(n0 + srow) * KDIM + scol;

  // fragment read offsets: row = base + r16, k-step granule (ks*4+quad)^(row&7)
  const int r7   = r16 & 7;
  const int g0   = (quad ^ r7) * 16;
  const int g1   = ((4 | quad) ^ r7) * 16;
  const int arow = (wr * 128 + r16) * 128;
  const int brow = (wc * 64 + r16) * 128;

  f32x4 acc[8][4];
#pragma unroll
  for (int i = 0; i < 8; ++i)
#pragma unroll
    for (int j = 0; j < 4; ++j) acc[i][j] = f32x4{0.f, 0.f, 0.f, 0.f};

  bf16x8 b0[4], b1[4];

  // prologue: buf0 <- tile0 (A+B), buf1.B <- tile1; vmcnt(4) retires buf0's 8
  STG2(0, 0, 0, gA, 0); STG2(0, 0, 1, gA, 0);
  STG2(0, 1, 0, gB, 0); STG2(0, 1, 1, gB, 0);
  STG2(1, 1, 0, gB, 64); STG2(1, 1, 1, gB, 64);
  BARV4;

  for (int s = 0; s < NITER; ++s) {
    const bool nl = (s + 1 < NITER);
    // ---- buf0 phases (tile 2s) ----
    PH(0, 0, 0,    g0, b0, 1, STG2(1, 0, 0, gA, 64), BAR)
    PH(0, 0, 0,    g1, b1, 1, STG2(1, 0, 1, gA, 64), BAR)
    PH(0, 4, 8192, g0, b0, 0, if (nl) STG2(0, 1, 0, gB, 128), BAR)
    PH(0, 4, 8192, g1, b1, 0, if (nl) STG2(0, 1, 1, gB, 128),
       if (nl) { BARV4; } else { BARV0; })
    // ---- buf1 phases (tile 2s+1) ----
    PH(1, 0, 0,    g0, b0, 1, if (nl) STG2(0, 0, 0, gA, 128), BAR)
    PH(1, 0, 0,    g1, b1, 1, if (nl) STG2(0, 0, 1, gA, 128), BAR)
    PH(1, 4, 8192, g0, b0, 0, if (nl) STG2(1, 1, 0, gB, 192), BAR)
    PH(1, 4, 8192, g1, b1, 0, if (nl) STG2(1, 1, 1, gB, 192),
       if (nl) { BARV4; } else { BARV0; })
    gA += 128; gB += 128;
  }

  // ---- epilogue ----
  // C/D layout: col = n0 + wc*64 + j*16 + r16, row = m0 + wr*128 + i*16 + quad*4 + r
  if (PASS == 0) {
#pragma unroll
    for (int j = 0; j < 4; ++j) {
      const int col = n0 + wc * 64 + j * 16 + r16;
#pragma unroll
      for (int i = 0; i < 8; ++i) {
        const int row = m0 + wr * 128 + i * 16 + quad * 4;
        f32x4 v = acc[i][j];
#pragma unroll
        for (int r = 0; r < 4; ++r) out[(size_t)(row + r) * ODIM + col] = v[r];
      }
    }
  } else {
    const float inv_rt2 = 0.70710678118654752f;
#pragma unroll
    for (int j = 0; j < 4; ++j) {
      const int col = n0 + wc * 64 + j * 16 + r16;
      const float sd  = sumd[col];
      const float sde = sumde[col] + EPSF;
#pragma unroll
      for (int i = 0; i < 8; ++i) {
        const int row = m0 + wr * 128 + i * 16 + quad * 4;
        f32x4 m4 = acc[i][j];
#pragma unroll
        for (int r = 0; r < 4; ++r) {
          float var = out[(size_t)(row + r) * ODIM + col] + sde;
          float mu  = m4[r] + sd;
          float z = (TM05 - mu) * rsqrtf(var) * inv_rt2;
          out[(size_t)(row + r) * ODIM + col] = 0.5f * erfcf(z);
        }
      }
    }
  }
}

// ---------------- launch ----------------
// ws layout (bytes):
//   0         : Cb   (33554432)
//   33554432  : C2b  (33554432)
//   67108864  : sumd (16384)
//   67125248  : sumde(16384)
//   67141632  : Xb   (67108864)
//   134250496 : Yb   (67108864)
extern "C" void kernel_launch(void* const* d_in, const int* in_sizes, int n_in,
                              void* d_out, int out_size, void* d_ws, size_t ws_size,
                              hipStream_t stream) {
  const float* p_x    = (const float*)d_in[0];
  const float* weight = (const float*)d_in[1];
  float* out = (float*)d_out;
  char* ws = (char*)d_ws;

  u16* Cb      = (u16*)(ws);
  u16* C2b     = (u16*)(ws + 33554432);
  float* sumd  = (float*)(ws + 67108864);
  float* sumde = (float*)(ws + 67125248);
  u16* Xb      = (u16*)(ws + 67141632);
  u16* Yb      = (u16*)(ws + 134250496);

  prep_w_kernel<<<ODIM, 256, 0, stream>>>((const float4*)weight, (ushort4*)Cb,
                                          (ushort4*)C2b, sumd, sumde);
  prep_x_kernel<<<(MDIM * KDIM / 4) / 256, 256, 0, stream>>>((const float4*)p_x,
                                                             (ushort4*)Xb,
                                                             (ushort4*)Yb);
  const int nwg = (MDIM / 256) * (ODIM / 256);  // 512
  gemm_pass_kernel<0><<<nwg, 512, 0, stream>>>(Yb, C2b, sumd, sumde, out);
  gemm_pass_kernel<1><<<nwg, 512, 0, stream>>>(Xb, Cb, sumd, sumde, out);
}